// Round 21
// baseline (455.353 us; speedup 1.0000x reference)
//
#include <hip/hip_runtime.h>
#include <hip/hip_bf16.h>
#include <stdint.h>

#define M_TOK 2048
#define HID   1024
#define NEXP  64
#define TOPK  6
#define TOTSLOT (M_TOK*TOPK)   // 12288

typedef unsigned short u16;
typedef __attribute__((ext_vector_type(4))) u16   u16x4;
typedef __attribute__((ext_vector_type(8))) u16   u16x8;
typedef __attribute__((ext_vector_type(4))) float f32x4;
typedef __attribute__((ext_vector_type(8))) short bf16x8;

// Native RNE fp32->bf16 (pairs fuse into v_cvt_pk_bf16_f32).
__device__ __forceinline__ u16 f2b(float f) {
    union { __hip_bfloat16 b; u16 u; } c;
    c.b = __float2bfloat16(f);
    return c.u;
}
__device__ __forceinline__ float b2f(u16 b) {
    union { uint32_t u; float f; } v; v.u = ((uint32_t)b) << 16; return v.f;
}

// ---------------- gw transpose: gwT[k][e] so router lanes read coalesced ----------------
__global__ __launch_bounds__(256) void transpose_gw_kernel(const float* __restrict__ gw,
                                                           float* __restrict__ gwT) {
    int i = blockIdx.x * 256 + threadIdx.x;   // 65536 elements
    int e = i >> 10, k = i & 1023;
    gwT[k * NEXP + e] = gw[i];
}

// ---------------- router: fp64 logits (coalesced gwT), grouped topk, + xb convert -----
__global__ __launch_bounds__(64) void router_kernel(
    const float* __restrict__ x, const float* __restrict__ gwT,
    u16* __restrict__ xb,
    int* __restrict__ topk_id, float* __restrict__ topk_w, int* __restrict__ counts)
{
    int t = blockIdx.x, lane = threadIdx.x;
    __shared__ float xr[HID];
    for (int k = lane; k < HID; k += 64) xr[k] = x[(size_t)t * HID + k];
    __syncthreads();
    // xb conversion riding along: lane covers 16 contiguous elems (32B store)
    {
        u16* xbr = xb + (size_t)t * HID + lane * 16;
        #pragma unroll
        for (int j = 0; j < 4; ++j) {
            u16x4 o;
            o[0] = f2b(xr[lane*16 + j*4 + 0]);
            o[1] = f2b(xr[lane*16 + j*4 + 1]);
            o[2] = f2b(xr[lane*16 + j*4 + 2]);
            o[3] = f2b(xr[lane*16 + j*4 + 3]);
            *reinterpret_cast<u16x4*>(xbr + j*4) = o;
        }
    }
    double s0 = 0.0, s1 = 0.0, s2 = 0.0, s3 = 0.0;
    for (int k = 0; k < HID; k += 4) {
        s0 += (double)xr[k]   * (double)gwT[(k)   * NEXP + lane];
        s1 += (double)xr[k+1] * (double)gwT[(k+1) * NEXP + lane];
        s2 += (double)xr[k+2] * (double)gwT[(k+2) * NEXP + lane];
        s3 += (double)xr[k+3] * (double)gwT[(k+3) * NEXP + lane];
    }
    double s = (s0 + s1) + (s2 + s3);
    __shared__ double lg[NEXP];
    __shared__ float  pr[NEXP];
    float sf = (float)s;
    float mx = sf;
    for (int o = 32; o; o >>= 1) mx = fmaxf(mx, __shfl_xor(mx, o));
    float ev = __expf(sf - mx);
    float sum = ev;
    for (int o = 32; o; o >>= 1) sum += __shfl_xor(sum, o);
    lg[lane] = s; pr[lane] = ev / sum;
    __syncthreads();
    if (lane == 0) {
        double gs[8];
        #pragma unroll
        for (int g = 0; g < 8; ++g) {
            double m = lg[g*8];
            #pragma unroll
            for (int i = 1; i < 8; ++i) m = fmax(m, lg[g*8+i]);
            gs[g] = m;
        }
        unsigned gsel = 0;
        for (int r = 0; r < 3; ++r) {
            int bi = 0; double bv = -1e300;
            for (int g = 0; g < 8; ++g)
                if (!((gsel>>g)&1u) && gs[g] > bv) { bv = gs[g]; bi = g; }
            gsel |= 1u << bi;
        }
        unsigned long long taken = 0;
        for (int r = 0; r < TOPK; ++r) {
            int bi = 0; double bv = -1e300;
            for (int e = 0; e < NEXP; ++e) {
                if (!((gsel >> (e>>3)) & 1u)) continue;
                if ((taken >> e) & 1ull) continue;
                if (lg[e] > bv) { bv = lg[e]; bi = e; }
            }
            taken |= 1ull << bi;
            topk_id[t*TOPK + r] = bi;
            topk_w[t*TOPK + r] = pr[bi];
            atomicAdd(&counts[bi], 1);
        }
    }
}

__global__ void scan_kernel(const int* __restrict__ counts, int* __restrict__ offs,
                            int* __restrict__ cursor) {
    if (threadIdx.x == 0) {
        int acc = 0;
        for (int e = 0; e < NEXP; ++e) { offs[e] = acc; cursor[e] = acc; acc += counts[e]; }
        offs[NEXP] = acc;
    }
}

__global__ __launch_bounds__(256) void fill_kernel(
    const int* __restrict__ topk_id, const float* __restrict__ topk_w,
    int* __restrict__ cursor, int* __restrict__ stok, float* __restrict__ sw,
    int* __restrict__ spos)
{
    int idx = blockIdx.x*256 + threadIdx.x;
    if (idx >= TOTSLOT) return;
    int e = topk_id[idx];
    int pos = atomicAdd(&cursor[e], 1);
    stok[pos] = idx / TOPK;
    sw[pos] = topk_w[idx];
    spos[idx] = pos;
}

// ---------------- GEMM core: BM=128, BN=128, BK=64, 512 thr, 2 blocks/CU --------------
// KIND 0: routed gate/up  A=xb[tok] K=1024, B=w1[e] -> h (silu*up*w, bf16)
// KIND 1: shared gate/up  A=xb      K=1024, B=sgu  -> hs (bf16)
// KIND 2: routed down     A=h       K=1024, B=w2[e]-> y  (bf16)
// KIND 3: shared down     A=hs      K=2048, B=sdn  -> Out (f32)
// B staging: 8 threads/row (q=0..7), lane q at +q*4 fp32, loads at +j*32 fp32 ->
// each global_load_dwordx4 fetches ONE FULL 128B cache line per row (8 lanes x 16B
// contiguous, 128B-aligned). Each thread covers rows {rb0, rb0+64}. Chunk math:
// E = q*4 + j*32 -> ch = (q>>1)+4j, half = q&1; swizzle (ch ^ (row&7)) unchanged.
template<int KIND>
__device__ __forceinline__ void gemm_core(
    const int e, const int my, const int nblk,
    const u16* __restrict__ A, const float* __restrict__ Bw,
    u16* __restrict__ Hout, float* __restrict__ Out,
    const int* __restrict__ offs, const int* __restrict__ stok,
    const float* __restrict__ sw,
    u16* __restrict__ AsR, u16* __restrict__ BsR,
    int* __restrict__ tkl, float* __restrict__ swl)
{
    constexpr bool G1     = (KIND == 0 || KIND == 1);
    constexpr bool ROUTED = (KIND == 0 || KIND == 2);
    constexpr int  BM     = 128;
    constexpr int  KD     = (KIND == 3) ? 2048 : 1024;
    constexpr int  KITER  = KD / 64;
    constexpr int  NPAIR  = (KIND == 0) ? 1024 : 2048;

    const int tid  = threadIdx.x;
    const int lane = tid & 63;
    const int wv   = tid >> 6;

    int off = 0, cnt = M_TOK;
    if (ROUTED) { off = offs[e]; cnt = offs[e+1] - off; }
    const int m0 = my * BM;
    if (m0 >= cnt) return;

    if (ROUTED && tid < BM) {
        int gr = m0 + tid;
        if (KIND == 0) {
            tkl[tid] = (gr < cnt) ? stok[off + gr] : 0;
            swl[tid] = (gr < cnt) ? sw[off + gr] : 0.f;
        } else {
            int r = off + gr; if (r > TOTSLOT-1) r = TOTSLOT-1;
            tkl[tid] = r;
        }
    }
    __syncthreads();

    // A staging: wave stages 8 rows/call (64 lanes x 16B = 1KB = 8 rows x 128B), 2 calls.
    const int acol8 = (lane & 7) ^ (lane >> 3);
    int aoff[2];
    #pragma unroll
    for (int j = 0; j < 2; ++j) {
        int r = wv*16 + j*8 + (lane >> 3);
        int arow = ROUTED ? tkl[r] : (m0 + r);
        aoff[j] = arow * KD + acol8 * 8;
    }

    const float* Be = Bw;
    if (KIND == 0) Be += (size_t)e * (size_t)(2*1024*1024);
    if (KIND == 2) Be += (size_t)e * (size_t)(1024*1024);
    // B staging: 8 threads/row; thread covers tile rows rb0 and rb0+64.
    const int rb0 = tid >> 3;            // 0..63
    const int q   = tid & 7;             // 0..7
    auto mapRow = [&](int r) -> int {
        if constexpr (G1) return (r < 64) ? (nblk*64 + r) : (NPAIR + nblk*64 + (r - 64));
        else              return nblk*128 + r;
    };
    const float* bsrc0 = Be + (size_t)mapRow(rb0)      * KD + q*4;
    const float* bsrc1 = Be + (size_t)mapRow(rb0 + 64) * KD + q*4;

    float4 br[4];

    auto stageA = [&](int buf, int k0) {
        #pragma unroll
        for (int j = 0; j < 2; ++j) {
            __builtin_amdgcn_global_load_lds(
                (const __attribute__((address_space(1))) uint32_t*)(A + (size_t)(aoff[j] + k0)),
                (__attribute__((address_space(3))) uint32_t*)(AsR + buf*(BM*64) + (wv*16 + j*8)*64),
                16, 0, 0);
        }
    };
    auto loadB = [&](int k0) {
        br[0] = *reinterpret_cast<const float4*>(bsrc0 + k0);
        br[1] = *reinterpret_cast<const float4*>(bsrc0 + k0 + 32);
        br[2] = *reinterpret_cast<const float4*>(bsrc1 + k0);
        br[3] = *reinterpret_cast<const float4*>(bsrc1 + k0 + 32);
    };
    auto storeB = [&](int buf) {
        char* base = (char*)(BsR + buf*(128*64));
        #pragma unroll
        for (int rs = 0; rs < 2; ++rs) {
            int row = rb0 + rs*64;
            char* bd = base + row*128;
            #pragma unroll
            for (int j = 0; j < 2; ++j) {
                const float4& v = br[rs*2 + j];
                u16x4 w;
                w[0] = f2b(v.x); w[1] = f2b(v.y); w[2] = f2b(v.z); w[3] = f2b(v.w);
                int ch = (q >> 1) + 4*j;     // element base q*4+j*32 -> chunk E>>3
                *reinterpret_cast<u16x4*>(bd + (((ch ^ (row & 7)) << 4) + (q & 1) * 8)) = w;
            }
        }
    };

    f32x4 acc[8];
    #pragma unroll
    for (int nf = 0; nf < 8; ++nf) acc[nf] = (f32x4){0.f, 0.f, 0.f, 0.f};

    auto mfma_phase = [&](int buf) {
        const char* Ab = (const char*)(AsR + buf*(BM*64));
        const char* Bb = (const char*)(BsR + buf*(128*64));
        #pragma unroll
        for (int kk = 0; kk < 2; ++kk) {
            const int sc = kk*4 + (lane >> 4);
            const int ra = wv*16 + (lane & 15);
            bf16x8 af = *reinterpret_cast<const bf16x8*>(Ab + ra*128 + ((sc ^ (ra & 7)) << 4));
            #pragma unroll
            for (int nf = 0; nf < 8; ++nf) {
                int rbb = nf*16 + (lane & 15);
                bf16x8 bfr = *reinterpret_cast<const bf16x8*>(Bb + rbb*128 + ((sc ^ (rbb & 7)) << 4));
                acc[nf] = __builtin_amdgcn_mfma_f32_16x16x32_bf16(af, bfr, acc[nf], 0, 0, 0);
            }
        }
    };

    stageA(0, 0);
    loadB(0);
    storeB(0);
    __syncthreads();

    for (int kt = 0; kt < KITER; ++kt) {
        const int cur = kt & 1, nxt = cur ^ 1;
        const bool more = (kt + 1 < KITER);
        if (more) { stageA(nxt, (kt + 1) * 64); loadB((kt + 1) * 64); }
        mfma_phase(cur);
        if (more) storeB(nxt);
        __syncthreads();
    }

    if constexpr (G1) {
        const int colbase = nblk*64 + (lane & 15);
        #pragma unroll
        for (int j = 0; j < 4; ++j) {
            int r = wv*16 + (lane >> 4)*4 + j;
            if (ROUTED && (m0 + r) >= cnt) continue;
            float wgt = (KIND == 0) ? swl[r] : 1.0f;
            size_t orow = (size_t)(ROUTED ? (off + m0 + r) : (m0 + r));
            #pragma unroll
            for (int nf = 0; nf < 4; ++nf) {
                float g = acc[nf][j];
                float u = acc[nf+4][j];
                float hv = (g / (1.f + __expf(-g))) * u * wgt;
                Hout[orow * NPAIR + colbase + nf*16] = f2b(hv);
            }
        }
    } else {
        const int colbase = nblk*128 + (lane & 15);
        #pragma unroll
        for (int j = 0; j < 4; ++j) {
            int r = wv*16 + (lane >> 4)*4 + j;
            if (ROUTED && (m0 + r) >= cnt) continue;
            #pragma unroll
            for (int nf = 0; nf < 8; ++nf) {
                float v = acc[nf][j];
                if (KIND == 2) Hout[(size_t)(off + m0 + r) * HID + colbase + nf*16] = f2b(v);
                else           Out[(size_t)(m0 + r) * HID + colbase + nf*16] = v;
            }
        }
    }
}

// ---- fused launch 1: routed gate/up (0..2047) + shared gate/up (2048..2559) ----
__global__ __launch_bounds__(512, 4) void gemm01_kernel(
    const u16* __restrict__ xb, const float* __restrict__ w1, const float* __restrict__ sgu,
    u16* __restrict__ h, u16* __restrict__ hs,
    const int* __restrict__ offs, const int* __restrict__ stok, const float* __restrict__ sw)
{
    __shared__ u16 AsR[2*128*64];
    __shared__ u16 BsR[2*128*64];
    __shared__ int   tkl[128];
    __shared__ float swl[128];
    const int rid = blockIdx.x;
    if (rid < 2048) {           // 8 experts/XCD, 32 blocks/expert (my 0..1, nblk 0..15)
        int slot = rid >> 3;
        int e = (rid & 7) * 8 + (slot >> 5);
        int sub = slot & 31;
        gemm_core<0>(e, sub >> 4, sub & 15, xb, w1, h, nullptr, offs, stok, sw, AsR, BsR, tkl, swl);
    } else {                    // shared gate/up: 512 blocks (my 0..15, nblk 0..31)
        int sid = rid - 2048;
        int slot = sid >> 3;
        gemm_core<1>(0, slot & 15, (sid & 7) * 4 + (slot >> 4), xb, sgu, hs, nullptr,
                     offs, stok, sw, AsR, BsR, tkl, swl);
    }
}

// ---- fused launch 2: shared down (0..127, K=2048, longest-first) + routed down ----
__global__ __launch_bounds__(512, 4) void gemm23_kernel(
    const u16* __restrict__ h, const u16* __restrict__ hs,
    const float* __restrict__ w2, const float* __restrict__ sdn,
    u16* __restrict__ y, float* __restrict__ out,
    const int* __restrict__ offs, const int* __restrict__ stok, const float* __restrict__ sw)
{
    __shared__ u16 AsR[2*128*64];
    __shared__ u16 BsR[2*128*64];
    __shared__ int   tkl[128];
    __shared__ float swl[128];
    const int rid = blockIdx.x;
    if (rid >= 128) {           // routed down: 8 experts/XCD (my 0..1, nblk 0..7)
        int r2 = rid - 128;
        int slot = r2 >> 3;
        int e = (r2 & 7) * 8 + (slot >> 4);
        int sub = slot & 15;
        gemm_core<2>(e, sub >> 3, sub & 7, h, w2, y, nullptr, offs, stok, sw, AsR, BsR, tkl, swl);
    } else {                    // shared down: 128 blocks (my 0..15, nblk 0..7)
        int slot = rid >> 3;
        gemm_core<3>(0, slot, rid & 7, hs, sdn, nullptr, out,
                     offs, stok, sw, AsR, BsR, tkl, swl);
    }
}

// ---------------- gather-reduce: out[t] += sum_k y[spos[t,k]] ----------------
__global__ __launch_bounds__(256) void reduce_kernel(
    const u16* __restrict__ y, const int* __restrict__ spos, float* __restrict__ out)
{
    int t = blockIdx.x;
    int c = threadIdx.x * 4;
    float4 o = *reinterpret_cast<const float4*>(out + (size_t)t*HID + c);
    #pragma unroll
    for (int k = 0; k < TOPK; ++k) {
        int p = spos[t*TOPK + k];
        u16x4 v = *reinterpret_cast<const u16x4*>(y + (size_t)p*HID + c);
        o.x += b2f(v[0]); o.y += b2f(v[1]); o.z += b2f(v[2]); o.w += b2f(v[3]);
    }
    *reinterpret_cast<float4*>(out + (size_t)t*HID + c) = o;
}

extern "C" void kernel_launch(void* const* d_in, const int* in_sizes, int n_in,
                              void* d_out, int out_size, void* d_ws, size_t ws_size,
                              hipStream_t stream)
{
    const float* x   = (const float*)d_in[0];
    const float* gw  = (const float*)d_in[1];
    const float* w1  = (const float*)d_in[2];
    const float* w2  = (const float*)d_in[3];
    const float* sgu = (const float*)d_in[4];
    const float* sdn = (const float*)d_in[5];
    float* out = (float*)d_out;

    char* p = (char*)d_ws;
    auto carve = [&](size_t bytes) { char* r = p; p += (bytes + 255) & ~(size_t)255; return r; };
    u16*   xb      = (u16*)  carve((size_t)M_TOK * HID * 2);
    u16*   h       = (u16*)  carve((size_t)TOTSLOT * 1024 * 2);
    u16*   hs      = (u16*)  carve((size_t)M_TOK * 2048 * 2);
    u16*   y       = (u16*)  carve((size_t)TOTSLOT * HID * 2);
    float* gwT     = (float*)carve((size_t)HID * NEXP * 4);
    int*   topk_id = (int*)  carve(M_TOK * TOPK * 4);
    float* topk_w  = (float*)carve(M_TOK * TOPK * 4);
    int*   counts  = (int*)  carve(NEXP * 4);
    int*   offs    = (int*)  carve((NEXP + 1) * 4);
    int*   cursor  = (int*)  carve(NEXP * 4);
    int*   stok    = (int*)  carve(TOTSLOT * 4);
    float* sw      = (float*)carve(TOTSLOT * 4);
    int*   spos    = (int*)  carve(TOTSLOT * 4);

    hipMemsetAsync(counts, 0, NEXP * 4, stream);
    transpose_gw_kernel<<<(NEXP*HID + 255)/256, 256, 0, stream>>>(gw, gwT);
    router_kernel<<<M_TOK, 64, 0, stream>>>(x, gwT, xb, topk_id, topk_w, counts);
    scan_kernel<<<1, 64, 0, stream>>>(counts, offs, cursor);
    fill_kernel<<<(TOTSLOT + 255)/256, 256, 0, stream>>>(topk_id, topk_w, cursor, stok, sw, spos);

    gemm01_kernel<<<2560, 512, 0, stream>>>(xb, w1, sgu, h, hs, offs, stok, sw);
    gemm23_kernel<<<1152, 512, 0, stream>>>(h, hs, w2, sdn, y, out, offs, stok, sw);
    reduce_kernel<<<M_TOK, 256, 0, stream>>>(y, spos, out);
}

// Round 22
// 442.446 us; speedup vs baseline: 1.0292x; 1.0292x over previous
//
#include <hip/hip_runtime.h>
#include <hip/hip_bf16.h>
#include <stdint.h>

#define M_TOK 2048
#define HID   1024
#define NEXP  64
#define TOPK  6
#define TOTSLOT (M_TOK*TOPK)   // 12288

typedef unsigned short u16;
typedef __attribute__((ext_vector_type(4))) u16   u16x4;
typedef __attribute__((ext_vector_type(8))) u16   u16x8;
typedef __attribute__((ext_vector_type(4))) float f32x4;
typedef __attribute__((ext_vector_type(8))) short bf16x8;

// Native RNE fp32->bf16 (pairs fuse into v_cvt_pk_bf16_f32).
__device__ __forceinline__ u16 f2b(float f) {
    union { __hip_bfloat16 b; u16 u; } c;
    c.b = __float2bfloat16(f);
    return c.u;
}
__device__ __forceinline__ float b2f(u16 b) {
    union { uint32_t u; float f; } v; v.u = ((uint32_t)b) << 16; return v.f;
}

// ---------------- gw transpose: gwT[k][e] so router lanes read coalesced ----------------
__global__ __launch_bounds__(256) void transpose_gw_kernel(const float* __restrict__ gw,
                                                           float* __restrict__ gwT) {
    int i = blockIdx.x * 256 + threadIdx.x;   // 65536 elements
    int e = i >> 10, k = i & 1023;
    gwT[k * NEXP + e] = gw[i];
}

// ---------------- router: fp64 logits (coalesced gwT), grouped topk, + xb convert -----
__global__ __launch_bounds__(64) void router_kernel(
    const float* __restrict__ x, const float* __restrict__ gwT,
    u16* __restrict__ xb,
    int* __restrict__ topk_id, float* __restrict__ topk_w, int* __restrict__ counts)
{
    int t = blockIdx.x, lane = threadIdx.x;
    __shared__ float xr[HID];
    for (int k = lane; k < HID; k += 64) xr[k] = x[(size_t)t * HID + k];
    __syncthreads();
    // xb conversion riding along: lane covers 16 contiguous elems (32B store)
    {
        u16* xbr = xb + (size_t)t * HID + lane * 16;
        #pragma unroll
        for (int j = 0; j < 4; ++j) {
            u16x4 o;
            o[0] = f2b(xr[lane*16 + j*4 + 0]);
            o[1] = f2b(xr[lane*16 + j*4 + 1]);
            o[2] = f2b(xr[lane*16 + j*4 + 2]);
            o[3] = f2b(xr[lane*16 + j*4 + 3]);
            *reinterpret_cast<u16x4*>(xbr + j*4) = o;
        }
    }
    double s0 = 0.0, s1 = 0.0, s2 = 0.0, s3 = 0.0;
    for (int k = 0; k < HID; k += 4) {
        s0 += (double)xr[k]   * (double)gwT[(k)   * NEXP + lane];
        s1 += (double)xr[k+1] * (double)gwT[(k+1) * NEXP + lane];
        s2 += (double)xr[k+2] * (double)gwT[(k+2) * NEXP + lane];
        s3 += (double)xr[k+3] * (double)gwT[(k+3) * NEXP + lane];
    }
    double s = (s0 + s1) + (s2 + s3);
    __shared__ double lg[NEXP];
    __shared__ float  pr[NEXP];
    float sf = (float)s;
    float mx = sf;
    for (int o = 32; o; o >>= 1) mx = fmaxf(mx, __shfl_xor(mx, o));
    float ev = __expf(sf - mx);
    float sum = ev;
    for (int o = 32; o; o >>= 1) sum += __shfl_xor(sum, o);
    lg[lane] = s; pr[lane] = ev / sum;
    __syncthreads();
    if (lane == 0) {
        double gs[8];
        #pragma unroll
        for (int g = 0; g < 8; ++g) {
            double m = lg[g*8];
            #pragma unroll
            for (int i = 1; i < 8; ++i) m = fmax(m, lg[g*8+i]);
            gs[g] = m;
        }
        unsigned gsel = 0;
        for (int r = 0; r < 3; ++r) {
            int bi = 0; double bv = -1e300;
            for (int g = 0; g < 8; ++g)
                if (!((gsel>>g)&1u) && gs[g] > bv) { bv = gs[g]; bi = g; }
            gsel |= 1u << bi;
        }
        unsigned long long taken = 0;
        for (int r = 0; r < TOPK; ++r) {
            int bi = 0; double bv = -1e300;
            for (int e = 0; e < NEXP; ++e) {
                if (!((gsel >> (e>>3)) & 1u)) continue;
                if ((taken >> e) & 1ull) continue;
                if (lg[e] > bv) { bv = lg[e]; bi = e; }
            }
            taken |= 1ull << bi;
            topk_id[t*TOPK + r] = bi;
            topk_w[t*TOPK + r] = pr[bi];
            atomicAdd(&counts[bi], 1);
        }
    }
}

__global__ void scan_kernel(const int* __restrict__ counts, int* __restrict__ offs,
                            int* __restrict__ cursor) {
    if (threadIdx.x == 0) {
        int acc = 0;
        for (int e = 0; e < NEXP; ++e) { offs[e] = acc; cursor[e] = acc; acc += counts[e]; }
        offs[NEXP] = acc;
    }
}

__global__ __launch_bounds__(256) void fill_kernel(
    const int* __restrict__ topk_id, const float* __restrict__ topk_w,
    int* __restrict__ cursor, int* __restrict__ stok, float* __restrict__ sw,
    int* __restrict__ spos)
{
    int idx = blockIdx.x*256 + threadIdx.x;
    if (idx >= TOTSLOT) return;
    int e = topk_id[idx];
    int pos = atomicAdd(&cursor[e], 1);
    stok[pos] = idx / TOPK;
    sw[pos] = topk_w[idx];
    spos[idx] = pos;
}

// ---------------- GEMM core: BM=128, BN=128, BK=64, 512 thr, 2 blocks/CU (R19/R20) ----
// KIND 0: routed gate/up  A=xb[tok] K=1024, B=w1[e] -> h (silu*up*w, bf16)
// KIND 1: shared gate/up  A=xb      K=1024, B=sgu  -> hs (bf16)
// KIND 2: routed down     A=h       K=1024, B=w2[e]-> y  (bf16)
// KIND 3: shared down     A=hs      K=2048, B=sdn  -> Out (f32)
// B-load mapping: lane q covers q*16 bytes within the row, loads j at +j*64B -> each
// global_load_dwordx4 fetches 64B FULLY CONTIGUOUS per row. LDS layout/swizzle and
// everything else identical to the verified R19/R20 kernel (best: 443.5 us).
template<int KIND>
__device__ __forceinline__ void gemm_core(
    const int e, const int my, const int nblk,
    const u16* __restrict__ A, const float* __restrict__ Bw,
    u16* __restrict__ Hout, float* __restrict__ Out,
    const int* __restrict__ offs, const int* __restrict__ stok,
    const float* __restrict__ sw,
    u16* __restrict__ AsR, u16* __restrict__ BsR,
    int* __restrict__ tkl, float* __restrict__ swl)
{
    constexpr bool G1     = (KIND == 0 || KIND == 1);
    constexpr bool ROUTED = (KIND == 0 || KIND == 2);
    constexpr int  BM     = 128;
    constexpr int  KD     = (KIND == 3) ? 2048 : 1024;
    constexpr int  KITER  = KD / 64;
    constexpr int  NPAIR  = (KIND == 0) ? 1024 : 2048;

    const int tid  = threadIdx.x;
    const int lane = tid & 63;
    const int wv   = tid >> 6;

    int off = 0, cnt = M_TOK;
    if (ROUTED) { off = offs[e]; cnt = offs[e+1] - off; }
    const int m0 = my * BM;
    if (m0 >= cnt) return;

    if (ROUTED && tid < BM) {
        int gr = m0 + tid;
        if (KIND == 0) {
            tkl[tid] = (gr < cnt) ? stok[off + gr] : 0;
            swl[tid] = (gr < cnt) ? sw[off + gr] : 0.f;
        } else {
            int r = off + gr; if (r > TOTSLOT-1) r = TOTSLOT-1;
            tkl[tid] = r;
        }
    }
    __syncthreads();

    // A staging: wave stages 8 rows/call (64 lanes x 16B = 1KB = 8 rows x 128B), 2 calls.
    const int acol8 = (lane & 7) ^ (lane >> 3);
    int aoff[2];
    #pragma unroll
    for (int j = 0; j < 2; ++j) {
        int r = wv*16 + j*8 + (lane >> 3);
        int arow = ROUTED ? tkl[r] : (m0 + r);
        aoff[j] = arow * KD + acol8 * 8;
    }

    const float* Be = Bw;
    if (KIND == 0) Be += (size_t)e * (size_t)(2*1024*1024);
    if (KIND == 2) Be += (size_t)e * (size_t)(1024*1024);
    // B staging: 128 rows x 64 fp32; 4 threads/row. Lane q at +q*4 fp32, loads at +j*16:
    // per instruction the 4 lanes of a row are CONTIGUOUS (64B segment).
    const int rb = tid >> 2;
    const int q  = tid & 3;
    int brow;
    if (G1) brow = (rb < 64) ? (nblk*64 + rb) : (NPAIR + nblk*64 + (rb - 64));
    else    brow = nblk*128 + rb;
    const float* bsrc = Be + (size_t)brow * KD + q*4;

    float4 br[4];

    auto stageA = [&](int buf, int k0) {
        #pragma unroll
        for (int j = 0; j < 2; ++j) {
            __builtin_amdgcn_global_load_lds(
                (const __attribute__((address_space(1))) uint32_t*)(A + (size_t)(aoff[j] + k0)),
                (__attribute__((address_space(3))) uint32_t*)(AsR + buf*(BM*64) + (wv*16 + j*8)*64),
                16, 0, 0);
        }
    };
    auto loadB = [&](int k0) {
        #pragma unroll
        for (int j = 0; j < 4; ++j)
            br[j] = *reinterpret_cast<const float4*>(bsrc + k0 + j*16);
    };
    auto storeB = [&](int buf) {
        char* bd = (char*)(BsR + buf*(128*64)) + rb*128;
        #pragma unroll
        for (int j = 0; j < 4; ++j) {
            u16x4 w;
            w[0] = f2b(br[j].x); w[1] = f2b(br[j].y);
            w[2] = f2b(br[j].z); w[3] = f2b(br[j].w);
            int ch = (q >> 1) + 2*j;          // element base q*4+j*16 -> chunk E>>3
            *reinterpret_cast<u16x4*>(bd + (((ch ^ (rb & 7)) << 4) + (q & 1) * 8)) = w;
        }
    };

    f32x4 acc[8];
    #pragma unroll
    for (int nf = 0; nf < 8; ++nf) acc[nf] = (f32x4){0.f, 0.f, 0.f, 0.f};

    auto mfma_phase = [&](int buf) {
        const char* Ab = (const char*)(AsR + buf*(BM*64));
        const char* Bb = (const char*)(BsR + buf*(128*64));
        #pragma unroll
        for (int kk = 0; kk < 2; ++kk) {
            const int sc = kk*4 + (lane >> 4);
            const int ra = wv*16 + (lane & 15);
            bf16x8 af = *reinterpret_cast<const bf16x8*>(Ab + ra*128 + ((sc ^ (ra & 7)) << 4));
            #pragma unroll
            for (int nf = 0; nf < 8; ++nf) {
                int rbb = nf*16 + (lane & 15);
                bf16x8 bfr = *reinterpret_cast<const bf16x8*>(Bb + rbb*128 + ((sc ^ (rbb & 7)) << 4));
                acc[nf] = __builtin_amdgcn_mfma_f32_16x16x32_bf16(af, bfr, acc[nf], 0, 0, 0);
            }
        }
    };

    stageA(0, 0);
    loadB(0);
    storeB(0);
    __syncthreads();

    for (int kt = 0; kt < KITER; ++kt) {
        const int cur = kt & 1, nxt = cur ^ 1;
        const bool more = (kt + 1 < KITER);
        if (more) { stageA(nxt, (kt + 1) * 64); loadB((kt + 1) * 64); }
        mfma_phase(cur);
        if (more) storeB(nxt);
        __syncthreads();
    }

    if constexpr (G1) {
        const int colbase = nblk*64 + (lane & 15);
        #pragma unroll
        for (int j = 0; j < 4; ++j) {
            int r = wv*16 + (lane >> 4)*4 + j;
            if (ROUTED && (m0 + r) >= cnt) continue;
            float wgt = (KIND == 0) ? swl[r] : 1.0f;
            size_t orow = (size_t)(ROUTED ? (off + m0 + r) : (m0 + r));
            #pragma unroll
            for (int nf = 0; nf < 4; ++nf) {
                float g = acc[nf][j];
                float u = acc[nf+4][j];
                float hv = (g / (1.f + __expf(-g))) * u * wgt;
                Hout[orow * NPAIR + colbase + nf*16] = f2b(hv);
            }
        }
    } else {
        const int colbase = nblk*128 + (lane & 15);
        #pragma unroll
        for (int j = 0; j < 4; ++j) {
            int r = wv*16 + (lane >> 4)*4 + j;
            if (ROUTED && (m0 + r) >= cnt) continue;
            #pragma unroll
            for (int nf = 0; nf < 8; ++nf) {
                float v = acc[nf][j];
                if (KIND == 2) Hout[(size_t)(off + m0 + r) * HID + colbase + nf*16] = f2b(v);
                else           Out[(size_t)(m0 + r) * HID + colbase + nf*16] = v;
            }
        }
    }
}

// ---- fused launch 1: routed gate/up (0..2047) + shared gate/up (2048..2559) ----
__global__ __launch_bounds__(512, 4) void gemm01_kernel(
    const u16* __restrict__ xb, const float* __restrict__ w1, const float* __restrict__ sgu,
    u16* __restrict__ h, u16* __restrict__ hs,
    const int* __restrict__ offs, const int* __restrict__ stok, const float* __restrict__ sw)
{
    __shared__ u16 AsR[2*128*64];
    __shared__ u16 BsR[2*128*64];
    __shared__ int   tkl[128];
    __shared__ float swl[128];
    const int rid = blockIdx.x;
    if (rid < 2048) {           // 8 experts/XCD, 32 blocks/expert (my 0..1, nblk 0..15)
        int slot = rid >> 3;
        int e = (rid & 7) * 8 + (slot >> 5);
        int sub = slot & 31;
        gemm_core<0>(e, sub >> 4, sub & 15, xb, w1, h, nullptr, offs, stok, sw, AsR, BsR, tkl, swl);
    } else {                    // shared gate/up: 512 blocks (my 0..15, nblk 0..31)
        int sid = rid - 2048;
        int slot = sid >> 3;
        gemm_core<1>(0, slot & 15, (sid & 7) * 4 + (slot >> 4), xb, sgu, hs, nullptr,
                     offs, stok, sw, AsR, BsR, tkl, swl);
    }
}

// ---- fused launch 2: shared down (0..127, K=2048, longest-first) + routed down ----
__global__ __launch_bounds__(512, 4) void gemm23_kernel(
    const u16* __restrict__ h, const u16* __restrict__ hs,
    const float* __restrict__ w2, const float* __restrict__ sdn,
    u16* __restrict__ y, float* __restrict__ out,
    const int* __restrict__ offs, const int* __restrict__ stok, const float* __restrict__ sw)
{
    __shared__ u16 AsR[2*128*64];
    __shared__ u16 BsR[2*128*64];
    __shared__ int   tkl[128];
    __shared__ float swl[128];
    const int rid = blockIdx.x;
    if (rid >= 128) {           // routed down: 8 experts/XCD (my 0..1, nblk 0..7)
        int r2 = rid - 128;
        int slot = r2 >> 3;
        int e = (r2 & 7) * 8 + (slot >> 4);
        int sub = slot & 15;
        gemm_core<2>(e, sub >> 3, sub & 7, h, w2, y, nullptr, offs, stok, sw, AsR, BsR, tkl, swl);
    } else {                    // shared down: 128 blocks (my 0..15, nblk 0..7)
        int slot = rid >> 3;
        gemm_core<3>(0, slot, rid & 7, hs, sdn, nullptr, out,
                     offs, stok, sw, AsR, BsR, tkl, swl);
    }
}

// ---------------- gather-reduce: out[t] += sum_k y[spos[t,k]] ----------------
__global__ __launch_bounds__(256) void reduce_kernel(
    const u16* __restrict__ y, const int* __restrict__ spos, float* __restrict__ out)
{
    int t = blockIdx.x;
    int c = threadIdx.x * 4;
    float4 o = *reinterpret_cast<const float4*>(out + (size_t)t*HID + c);
    #pragma unroll
    for (int k = 0; k < TOPK; ++k) {
        int p = spos[t*TOPK + k];
        u16x4 v = *reinterpret_cast<const u16x4*>(y + (size_t)p*HID + c);
        o.x += b2f(v[0]); o.y += b2f(v[1]); o.z += b2f(v[2]); o.w += b2f(v[3]);
    }
    *reinterpret_cast<float4*>(out + (size_t)t*HID + c) = o;
}

extern "C" void kernel_launch(void* const* d_in, const int* in_sizes, int n_in,
                              void* d_out, int out_size, void* d_ws, size_t ws_size,
                              hipStream_t stream)
{
    const float* x   = (const float*)d_in[0];
    const float* gw  = (const float*)d_in[1];
    const float* w1  = (const float*)d_in[2];
    const float* w2  = (const float*)d_in[3];
    const float* sgu = (const float*)d_in[4];
    const float* sdn = (const float*)d_in[5];
    float* out = (float*)d_out;

    char* p = (char*)d_ws;
    auto carve = [&](size_t bytes) { char* r = p; p += (bytes + 255) & ~(size_t)255; return r; };
    u16*   xb      = (u16*)  carve((size_t)M_TOK * HID * 2);
    u16*   h       = (u16*)  carve((size_t)TOTSLOT * 1024 * 2);
    u16*   hs      = (u16*)  carve((size_t)M_TOK * 2048 * 2);
    u16*   y       = (u16*)  carve((size_t)TOTSLOT * HID * 2);
    float* gwT     = (float*)carve((size_t)HID * NEXP * 4);
    int*   topk_id = (int*)  carve(M_TOK * TOPK * 4);
    float* topk_w  = (float*)carve(M_TOK * TOPK * 4);
    int*   counts  = (int*)  carve(NEXP * 4);
    int*   offs    = (int*)  carve((NEXP + 1) * 4);
    int*   cursor  = (int*)  carve(NEXP * 4);
    int*   stok    = (int*)  carve(TOTSLOT * 4);
    float* sw      = (float*)carve(TOTSLOT * 4);
    int*   spos    = (int*)  carve(TOTSLOT * 4);

    hipMemsetAsync(counts, 0, NEXP * 4, stream);
    transpose_gw_kernel<<<(NEXP*HID + 255)/256, 256, 0, stream>>>(gw, gwT);
    router_kernel<<<M_TOK, 64, 0, stream>>>(x, gwT, xb, topk_id, topk_w, counts);
    scan_kernel<<<1, 64, 0, stream>>>(counts, offs, cursor);
    fill_kernel<<<(TOTSLOT + 255)/256, 256, 0, stream>>>(topk_id, topk_w, cursor, stok, sw, spos);

    gemm01_kernel<<<2560, 512, 0, stream>>>(xb, w1, sgu, h, hs, offs, stok, sw);
    gemm23_kernel<<<1152, 512, 0, stream>>>(h, hs, w2, sdn, y, out, offs, stok, sw);
    reduce_kernel<<<M_TOK, 256, 0, stream>>>(y, spos, out);
}